// Round 1
// baseline (172.719 us; speedup 1.0000x reference)
//
#include <hip/hip_runtime.h>
#include <math.h>

#define BATCH 32
#define HQ 32
#define HKV 8
#define DHEAD 128
#define BS 16
#define MAXB 128
#define G 4            // HQ / HKV
#define NWAVES 16
#define NTHREADS (NWAVES * 64)

__global__ __launch_bounds__(NTHREADS) void paged_attn_kernel(
    const float* __restrict__ query,      // [B, HQ, D]
    const float* __restrict__ new_k,      // [B, HKV, D]
    const float* __restrict__ new_v,      // [B, HKV, D]
    const float* __restrict__ k_cache,    // [NUM_BLOCKS, BS, HKV, D]
    const float* __restrict__ v_cache,    // [NUM_BLOCKS, BS, HKV, D]
    const int*   __restrict__ block_table,// [B, MAXB]
    const int*   __restrict__ context_lens,// [B]
    float*       __restrict__ out)        // [B, HQ, D]
{
    const int bid  = blockIdx.x;   // 0..B*HKV-1
    const int b    = bid >> 3;
    const int kv   = bid & 7;
    const int tid  = threadIdx.x;
    const int w    = tid >> 6;
    const int lane = tid & 63;

    __shared__ float s_cos[64], s_sin[64];
    __shared__ float s_q[G][DHEAD];
    __shared__ float s_knew[DHEAD], s_vnew[DHEAD];
    __shared__ float s_m[NWAVES][G];
    __shared__ float s_l[NWAVES][G];
    __shared__ float s_acc[NWAVES][G][DHEAD];   // 32 KB

    const int pos = context_lens[b];
    const int len = pos + 1;

    // ---- RoPE tables (f64 for accuracy; 64 values, once per block) ----
    if (w == 0) {
        double f = (double)pos * pow(10000.0, -(double)lane / 64.0);
        s_cos[lane] = (float)cos(f);
        s_sin[lane] = (float)sin(f);
    }
    __syncthreads();

    const float scale = 0.08838834764831845f;   // 1/sqrt(128)

    // ---- RoPE q (fold in scale), RoPE new_k, stage new_v ----
    if (tid < G * DHEAD) {                      // 512 threads: q
        int h = tid >> 7;
        int d = tid & 127;
        const float* qp = query + ((size_t)b * HQ + kv * G + h) * DHEAD;
        float x = qp[d], r;
        if (d < 64) r = x * s_cos[d]      - qp[d + 64] * s_sin[d];
        else        r = x * s_cos[d - 64] + qp[d - 64] * s_sin[d - 64];
        s_q[h][d] = r * scale;
    } else if (tid < G * DHEAD + DHEAD) {       // 128 threads: new_k
        int d = tid - G * DHEAD;
        const float* kp = new_k + ((size_t)b * HKV + kv) * DHEAD;
        float x = kp[d], r;
        if (d < 64) r = x * s_cos[d]      - kp[d + 64] * s_sin[d];
        else        r = x * s_cos[d - 64] + kp[d - 64] * s_sin[d - 64];
        s_knew[d] = r;
    } else if (tid < G * DHEAD + 2 * DHEAD) {   // 128 threads: new_v
        int d = tid - G * DHEAD - DHEAD;
        s_vnew[d] = new_v[((size_t)b * HKV + kv) * DHEAD + d];
    }
    __syncthreads();

    // ---- per-wave q fragment: 2 dims per lane, all 4 heads ----
    const int d0 = lane * 2;
    float q0[G], q1[G];
    #pragma unroll
    for (int h = 0; h < G; h++) { q0[h] = s_q[h][d0]; q1[h] = s_q[h][d0 + 1]; }

    float m[G], l[G], a0[G], a1[G];
    #pragma unroll
    for (int h = 0; h < G; h++) { m[h] = -1e30f; l[h] = 0.f; a0[h] = 0.f; a1[h] = 0.f; }

    const int* bt = block_table + b * MAXB;

    // ---- sequence scan: wave w takes positions w, w+16, ... ----
    for (int p = w; p < len; p += NWAVES) {
        float kx, ky, vx, vy;
        if (p == pos) {                         // functional cache update
            kx = s_knew[d0]; ky = s_knew[d0 + 1];
            vx = s_vnew[d0]; vy = s_vnew[d0 + 1];
        } else {
            int blk = bt[p >> 4];
            size_t row = (((size_t)blk * BS + (p & 15)) * HKV + kv) * DHEAD;
            float2 k2 = *(const float2*)(k_cache + row + d0);
            float2 v2 = *(const float2*)(v_cache + row + d0);
            kx = k2.x; ky = k2.y; vx = v2.x; vy = v2.y;
        }
        float dot[G];
        #pragma unroll
        for (int h = 0; h < G; h++) dot[h] = q0[h] * kx + q1[h] * ky;
        #pragma unroll
        for (int off = 1; off < 64; off <<= 1) {
            #pragma unroll
            for (int h = 0; h < G; h++) dot[h] += __shfl_xor(dot[h], off, 64);
        }
        #pragma unroll
        for (int h = 0; h < G; h++) {
            float s   = dot[h];
            float mn  = fmaxf(m[h], s);
            float cor = __expf(m[h] - mn);
            float wg  = __expf(s - mn);
            l[h]  = l[h]  * cor + wg;
            a0[h] = a0[h] * cor + wg * vx;
            a1[h] = a1[h] * cor + wg * vy;
            m[h]  = mn;
        }
    }

    // ---- write per-wave partials ----
    #pragma unroll
    for (int h = 0; h < G; h++) {
        s_acc[w][h][d0]     = a0[h];
        s_acc[w][h][d0 + 1] = a1[h];
    }
    if (lane == 0) {
        #pragma unroll
        for (int h = 0; h < G; h++) { s_m[w][h] = m[h]; s_l[w][h] = l[h]; }
    }
    __syncthreads();

    // ---- combine 16 wave-partials, write out ----
    if (tid < G * DHEAD) {
        int h = tid >> 7;
        int d = tid & 127;
        float mg = -1e30f;
        #pragma unroll
        for (int ww = 0; ww < NWAVES; ww++) mg = fmaxf(mg, s_m[ww][h]);
        float lsum = 0.f, asum = 0.f;
        #pragma unroll
        for (int ww = 0; ww < NWAVES; ww++) {
            float e = __expf(s_m[ww][h] - mg);
            lsum += s_l[ww][h] * e;
            asum += s_acc[ww][h][d] * e;
        }
        out[((size_t)b * HQ + kv * G + h) * DHEAD + d] = asum / lsum;
    }
}

extern "C" void kernel_launch(void* const* d_in, const int* in_sizes, int n_in,
                              void* d_out, int out_size, void* d_ws, size_t ws_size,
                              hipStream_t stream) {
    const float* query        = (const float*)d_in[0];
    const float* new_k        = (const float*)d_in[1];
    const float* new_v        = (const float*)d_in[2];
    const float* k_cache      = (const float*)d_in[3];
    const float* v_cache      = (const float*)d_in[4];
    const int*   block_table  = (const int*)d_in[5];
    const int*   context_lens = (const int*)d_in[6];
    float* out = (float*)d_out;

    dim3 grid(BATCH * HKV);
    dim3 block(NTHREADS);
    paged_attn_kernel<<<grid, block, 0, stream>>>(
        query, new_k, new_v, k_cache, v_cache, block_table, context_lens, out);
}

// Round 2
// 95.233 us; speedup vs baseline: 1.8137x; 1.8137x over previous
//
#include <hip/hip_runtime.h>
#include <math.h>

#define BATCH 32
#define HQ 32
#define HKV 8
#define DHEAD 128
#define BS 16
#define MAXB 128
#define G 4              // HQ / HKV
#define CHUNK 256        // positions per chunk-block
#define MAXCH 8          // LMAX / CHUNK = 2048/256
#define NW 4             // waves per chunk block
#define NT (NW * 64)     // 256 threads

// d_ws layout: wsacc[B*HKV*MAXCH][G*DHEAD] floats, then wsl[B*HKV*MAXCH][G]
#define NSLOT (BATCH * HKV * MAXCH)

__global__ __launch_bounds__(NT) void paged_attn_chunk(
    const float* __restrict__ query,       // [B, HQ, D]
    const float* __restrict__ new_k,       // [B, HKV, D]
    const float* __restrict__ new_v,       // [B, HKV, D]
    const float* __restrict__ k_cache,     // [NUM_BLOCKS, BS, HKV, D]
    const float* __restrict__ v_cache,     // [NUM_BLOCKS, BS, HKV, D]
    const int*   __restrict__ block_table, // [B, MAXB]
    const int*   __restrict__ context_lens,// [B]
    float*       __restrict__ wsacc,       // [NSLOT][G*DHEAD]
    float*       __restrict__ wsl)         // [NSLOT][G]
{
    const int c   = blockIdx.x & (MAXCH - 1);
    const int bkv = blockIdx.x >> 3;
    const int kv  = bkv & 7;
    const int b   = bkv >> 3;

    const int pos = context_lens[b];
    const int len = pos + 1;
    const int c0  = c * CHUNK;
    if (c0 >= len) return;                 // whole block exits together

    const int tid  = threadIdx.x;
    const int w    = tid >> 6;
    const int lane = tid & 63;
    const int grp  = lane >> 4;            // 4 groups of 16 lanes
    const int sub  = lane & 15;            // lane within group -> dims sub*8..+7

    __shared__ float s_cos[64], s_sin[64];
    __shared__ float s_q[G][DHEAD];
    __shared__ float s_knew[DHEAD], s_vnew[DHEAD];
    __shared__ int   s_bt[CHUNK / BS];     // 16 block ids for this chunk
    __shared__ float s_wacc[NW][G][DHEAD]; // 8 KB
    __shared__ float s_wl[NW][G];

    // ---- RoPE tables (f64, once) ----
    if (tid < 64) {
        double f = (double)pos * pow(10000.0, -(double)tid / 64.0);
        s_cos[tid] = (float)cos(f);
        s_sin[tid] = (float)sin(f);
    }
    __syncthreads();

    const float scale = 0.08838834764831845f;  // 1/sqrt(128)

    // ---- stage q (RoPE, scale folded), new_k (RoPE), new_v, block table ----
    for (int idx = tid; idx < G * DHEAD; idx += NT) {
        int h = idx >> 7, d = idx & 127;
        const float* qp = query + ((size_t)b * HQ + kv * G + h) * DHEAD;
        float x = qp[d], r;
        if (d < 64) r = x * s_cos[d]      - qp[d + 64] * s_sin[d];
        else        r = x * s_cos[d - 64] + qp[d - 64] * s_sin[d - 64];
        s_q[h][d] = r * scale;
    }
    if (tid < DHEAD) {
        int d = tid;
        const float* kp = new_k + ((size_t)b * HKV + kv) * DHEAD;
        float x = kp[d], r;
        if (d < 64) r = x * s_cos[d]      - kp[d + 64] * s_sin[d];
        else        r = x * s_cos[d - 64] + kp[d - 64] * s_sin[d - 64];
        s_knew[d] = r;
    } else if (tid < 2 * DHEAD) {
        int d = tid - DHEAD;
        s_vnew[d] = new_v[((size_t)b * HKV + kv) * DHEAD + d];
    }
    if (tid < CHUNK / BS) s_bt[tid] = block_table[b * MAXB + (c0 >> 4) + tid];
    __syncthreads();

    // ---- per-lane q fragment: 8 dims x 4 heads ----
    float qr[G][8];
    #pragma unroll
    for (int h = 0; h < G; h++)
        #pragma unroll
        for (int j = 0; j < 8; j++) qr[h][j] = s_q[h][sub * 8 + j];

    float acc[G][8];
    float l[G];
    #pragma unroll
    for (int h = 0; h < G; h++) {
        l[h] = 0.f;
        #pragma unroll
        for (int j = 0; j < 8; j++) acc[h][j] = 0.f;
    }

    // wave w owns positions [c0 + w*64, c0 + w*64 + 64), 4 at a time (one per group)
    const int base = c0 + w * 64;
    int rem = len - base;
    int a = rem < 0 ? 0 : (rem > 64 ? 64 : rem);
    int nfull = a >> 2;
    int tail  = a & 3;

#define BODY(GUARDED)                                                          \
    {                                                                          \
        int slot = w * 64 + it * 4 + grp;                                      \
        int pi   = c0 + slot;                                                  \
        bool act = !(GUARDED) || (grp < tail);                                 \
        float4 ka, kb, va, vb;                                                 \
        if (act) {                                                             \
            int blk = s_bt[slot >> 4];                                         \
            const float* kp = k_cache +                                        \
                (((size_t)blk * BS + (slot & 15)) * HKV + kv) * DHEAD + sub*8; \
            const float* vp = v_cache +                                        \
                (((size_t)blk * BS + (slot & 15)) * HKV + kv) * DHEAD + sub*8; \
            ka = *(const float4*)(kp);     kb = *(const float4*)(kp + 4);      \
            va = *(const float4*)(vp);     vb = *(const float4*)(vp + 4);      \
            if (pi == pos) {                                                   \
                ka = *(const float4*)(s_knew + sub*8);                         \
                kb = *(const float4*)(s_knew + sub*8 + 4);                     \
                va = *(const float4*)(s_vnew + sub*8);                         \
                vb = *(const float4*)(s_vnew + sub*8 + 4);                     \
            }                                                                  \
        }                                                                      \
        float dot[G];                                                          \
        if (act) {                                                             \
            _Pragma("unroll")                                                  \
            for (int h = 0; h < G; h++)                                        \
                dot[h] = qr[h][0]*ka.x + qr[h][1]*ka.y + qr[h][2]*ka.z +       \
                         qr[h][3]*ka.w + qr[h][4]*kb.x + qr[h][5]*kb.y +       \
                         qr[h][6]*kb.z + qr[h][7]*kb.w;                        \
        } else {                                                               \
            _Pragma("unroll")                                                  \
            for (int h = 0; h < G; h++) dot[h] = 0.f;                          \
        }                                                                      \
        _Pragma("unroll")                                                      \
        for (int off = 1; off < 16; off <<= 1) {                               \
            _Pragma("unroll")                                                  \
            for (int h = 0; h < G; h++) dot[h] += __shfl_xor(dot[h], off, 64); \
        }                                                                      \
        if (act) {                                                             \
            _Pragma("unroll")                                                  \
            for (int h = 0; h < G; h++) {                                      \
                float wg = __expf(dot[h]);                                     \
                l[h] += wg;                                                    \
                acc[h][0] += wg * va.x;  acc[h][1] += wg * va.y;               \
                acc[h][2] += wg * va.z;  acc[h][3] += wg * va.w;               \
                acc[h][4] += wg * vb.x;  acc[h][5] += wg * vb.y;               \
                acc[h][6] += wg * vb.z;  acc[h][7] += wg * vb.w;               \
            }                                                                  \
        }                                                                      \
    }

    #pragma unroll 2
    for (int it = 0; it < nfull; it++) BODY(false)
    if (tail) { int it = nfull; BODY(true) }
#undef BODY

    // ---- reduce across the 4 groups (lanes sub, sub+16, sub+32, sub+48) ----
    #pragma unroll
    for (int h = 0; h < G; h++) {
        l[h] += __shfl_xor(l[h], 16, 64);
        l[h] += __shfl_xor(l[h], 32, 64);
        #pragma unroll
        for (int j = 0; j < 8; j++) {
            acc[h][j] += __shfl_xor(acc[h][j], 16, 64);
            acc[h][j] += __shfl_xor(acc[h][j], 32, 64);
        }
    }
    if (lane < 16) {
        #pragma unroll
        for (int h = 0; h < G; h++)
            #pragma unroll
            for (int j = 0; j < 8; j++) s_wacc[w][h][sub * 8 + j] = acc[h][j];
    }
    if (lane == 0) {
        #pragma unroll
        for (int h = 0; h < G; h++) s_wl[w][h] = l[h];
    }
    __syncthreads();

    // ---- combine 4 wave-partials -> ws ----
    const size_t slot_base = (size_t)blockIdx.x * (G * DHEAD);
    for (int idx = tid; idx < G * DHEAD; idx += NT) {
        float s = s_wacc[0][0][0];  // dummy init pattern avoided; compute directly
        s = s_wacc[0][idx >> 7][idx & 127] + s_wacc[1][idx >> 7][idx & 127]
          + s_wacc[2][idx >> 7][idx & 127] + s_wacc[3][idx >> 7][idx & 127];
        wsacc[slot_base + idx] = s;
    }
    if (tid < G) {
        wsl[(size_t)blockIdx.x * G + tid] =
            s_wl[0][tid] + s_wl[1][tid] + s_wl[2][tid] + s_wl[3][tid];
    }
}

__global__ __launch_bounds__(512) void paged_attn_combine(
    const int*   __restrict__ context_lens,
    const float* __restrict__ wsacc,
    const float* __restrict__ wsl,
    float*       __restrict__ out)         // [B, HQ, D]
{
    const int bkv = blockIdx.x;            // 0..B*HKV-1
    const int kv  = bkv & 7;
    const int b   = bkv >> 3;
    const int t   = threadIdx.x;           // 0..511 -> (h, d)
    const int h   = t >> 7;
    const int d   = t & 127;

    const int len = context_lens[b] + 1;
    const int nch = (len + CHUNK - 1) >> 8;

    float asum = 0.f, lsum = 0.f;
    for (int cc = 0; cc < nch; cc++) {
        asum += wsacc[((size_t)bkv * MAXCH + cc) * (G * DHEAD) + t];
        lsum += wsl[((size_t)bkv * MAXCH + cc) * G + h];
    }
    out[((size_t)b * HQ + kv * G + h) * DHEAD + d] = asum / lsum;
}

extern "C" void kernel_launch(void* const* d_in, const int* in_sizes, int n_in,
                              void* d_out, int out_size, void* d_ws, size_t ws_size,
                              hipStream_t stream) {
    const float* query        = (const float*)d_in[0];
    const float* new_k        = (const float*)d_in[1];
    const float* new_v        = (const float*)d_in[2];
    const float* k_cache      = (const float*)d_in[3];
    const float* v_cache      = (const float*)d_in[4];
    const int*   block_table  = (const int*)d_in[5];
    const int*   context_lens = (const int*)d_in[6];
    float* out = (float*)d_out;

    float* wsacc = (float*)d_ws;                       // NSLOT * 512 floats
    float* wsl   = wsacc + (size_t)NSLOT * G * DHEAD;  // NSLOT * 4 floats

    paged_attn_chunk<<<dim3(BATCH * HKV * MAXCH), dim3(NT), 0, stream>>>(
        query, new_k, new_v, k_cache, v_cache, block_table, context_lens,
        wsacc, wsl);
    paged_attn_combine<<<dim3(BATCH * HKV), dim3(512), 0, stream>>>(
        context_lens, wsacc, wsl, out);
}

// Round 4
// 72.486 us; speedup vs baseline: 2.3828x; 1.3138x over previous
//
#include <hip/hip_runtime.h>
#include <math.h>

#define BATCH 32
#define HQ 32
#define HKV 8
#define DHEAD 128
#define BS 16
#define MAXB 128
#define G 4              // HQ / HKV
#define CHUNK 256        // positions per chunk-block
#define MAXCH 8          // LMAX / CHUNK
#define NW 4             // waves per chunk block
#define NT (NW * 64)

#define NSLOT (BATCH * HKV * MAXCH)

typedef float v2f __attribute__((ext_vector_type(2)));

__device__ __forceinline__ v2f pk_fma(v2f a, v2f b, v2f c) {
    v2f d;
    asm("v_pk_fma_f32 %0, %1, %2, %3" : "=v"(d) : "v"(a), "v"(b), "v"(c));
    return d;
}
__device__ __forceinline__ v2f pk_mul(v2f a, v2f b) {
    v2f d;
    asm("v_pk_mul_f32 %0, %1, %2" : "=v"(d) : "v"(a), "v"(b));
    return d;
}

// rotate-and-add step over each 16-lane row for 4 independent chains.
// leading s_nop 1 satisfies the "VALU write -> DPP src read needs 2 wait
// states" hazard for the freshest producer; within the block each chain is
// revisited only after >=3 instructions.
#define ROR4(N, x0, x1, x2, x3)                                                   \
    asm("s_nop 1\n\t"                                                             \
        "v_add_f32_dpp %0, %0, %0 row_ror:" #N " row_mask:0xf bank_mask:0xf\n\t"  \
        "v_add_f32_dpp %1, %1, %1 row_ror:" #N " row_mask:0xf bank_mask:0xf\n\t"  \
        "v_add_f32_dpp %2, %2, %2 row_ror:" #N " row_mask:0xf bank_mask:0xf\n\t"  \
        "v_add_f32_dpp %3, %3, %3 row_ror:" #N " row_mask:0xf bank_mask:0xf"      \
        : "+v"(x0), "+v"(x1), "+v"(x2), "+v"(x3))

__global__ __launch_bounds__(NT) void paged_attn_chunk(
    const float* __restrict__ query,
    const float* __restrict__ new_k,
    const float* __restrict__ new_v,
    const float* __restrict__ k_cache,
    const float* __restrict__ v_cache,
    const int*   __restrict__ block_table,
    const int*   __restrict__ context_lens,
    float*       __restrict__ wsacc,       // [NSLOT][G*DHEAD]
    float*       __restrict__ wsl)         // [NSLOT][G]
{
    const int c   = blockIdx.x & (MAXCH - 1);
    const int bkv = blockIdx.x >> 3;
    const int kv  = bkv & 7;
    const int b   = bkv >> 3;

    const int pos = context_lens[b];
    const int len = pos + 1;
    const int c0  = c * CHUNK;
    if (c0 >= len) return;

    const int tid  = threadIdx.x;
    const int w    = tid >> 6;
    const int lane = tid & 63;
    const int grp  = lane >> 4;
    const int sub  = lane & 15;

    __shared__ float s_cos[64], s_sin[64];
    __shared__ float s_q[G][DHEAD];
    __shared__ float s_knew[DHEAD], s_vnew[DHEAD];
    __shared__ int   s_bt[CHUNK / BS];
    __shared__ float s_wacc[NW][G][DHEAD];
    __shared__ float s_wl[NW][G];

    // ---- RoPE tables (f32) ----
    if (tid < 64) {
        // inv_freq = 10000^(-tid/64) = exp2(-tid * log2(10000)/64)
        float invf = exp2f((float)tid * -0.20762050593046014f);
        float ang  = (float)pos * invf;
        s_cos[tid] = cosf(ang);
        s_sin[tid] = sinf(ang);
    }
    __syncthreads();

    const float scale = 0.08838834764831845f;  // 1/sqrt(128)

    for (int idx = tid; idx < G * DHEAD; idx += NT) {
        int h = idx >> 7, d = idx & 127;
        const float* qp = query + ((size_t)b * HQ + kv * G + h) * DHEAD;
        float x = qp[d], r;
        if (d < 64) r = x * s_cos[d]      - qp[d + 64] * s_sin[d];
        else        r = x * s_cos[d - 64] + qp[d - 64] * s_sin[d - 64];
        s_q[h][d] = r * scale;
    }
    if (tid < DHEAD) {
        int d = tid;
        const float* kp = new_k + ((size_t)b * HKV + kv) * DHEAD;
        float x = kp[d], r;
        if (d < 64) r = x * s_cos[d]      - kp[d + 64] * s_sin[d];
        else        r = x * s_cos[d - 64] + kp[d - 64] * s_sin[d - 64];
        s_knew[d] = r;
    } else if (tid < 2 * DHEAD) {
        int d = tid - DHEAD;
        s_vnew[d] = new_v[((size_t)b * HKV + kv) * DHEAD + d];
    }
    if (tid < CHUNK / BS) s_bt[tid] = block_table[b * MAXB + (c0 >> 4) + tid];
    __syncthreads();

    // per-lane q fragment: 8 dims as 4 float2, x 4 heads
    v2f q2[G][4];
    #pragma unroll
    for (int h = 0; h < G; h++)
        #pragma unroll
        for (int j = 0; j < 4; j++)
            q2[h][j] = v2f{s_q[h][sub * 8 + 2 * j], s_q[h][sub * 8 + 2 * j + 1]};

    v2f acc2[G][4];
    float l[G];
    #pragma unroll
    for (int h = 0; h < G; h++) {
        l[h] = 0.f;
        #pragma unroll
        for (int j = 0; j < 4; j++) acc2[h][j] = v2f{0.f, 0.f};
    }

    const size_t lofs = (size_t)kv * DHEAD + sub * 8;

    const int base = c0 + w * 64;
    int rem = len - base;
    int a = rem < 0 ? 0 : (rem > 64 ? 64 : rem);
    int nfull = a >> 2;
    int tail  = a & 3;

#define BODY(GUARDED)                                                          \
    {                                                                          \
        int slot = w * 64 + it * 4 + grp;                                      \
        int pi   = c0 + slot;                                                  \
        bool act = !(GUARDED) || (grp < tail);                                 \
        v2f k2[4], u2[4];                                                      \
        _Pragma("unroll")                                                      \
        for (int j = 0; j < 4; j++) { k2[j] = v2f{0.f, 0.f}; u2[j] = v2f{0.f, 0.f}; } \
        if (act) {                                                             \
            int blk = s_bt[slot >> 4];                                         \
            size_t row = (size_t)blk * (BS * HKV * DHEAD)                      \
                       + (size_t)(slot & 15) * (HKV * DHEAD) + lofs;           \
            float4 ka = *(const float4*)(k_cache + row);                       \
            float4 kb = *(const float4*)(k_cache + row + 4);                   \
            float4 va = *(const float4*)(v_cache + row);                       \
            float4 vb = *(const float4*)(v_cache + row + 4);                   \
            if (pi == pos) {                                                   \
                ka = *(const float4*)(s_knew + sub * 8);                       \
                kb = *(const float4*)(s_knew + sub * 8 + 4);                   \
                va = *(const float4*)(s_vnew + sub * 8);                       \
                vb = *(const float4*)(s_vnew + sub * 8 + 4);                   \
            }                                                                  \
            k2[0] = v2f{ka.x, ka.y}; k2[1] = v2f{ka.z, ka.w};                  \
            k2[2] = v2f{kb.x, kb.y}; k2[3] = v2f{kb.z, kb.w};                  \
            u2[0] = v2f{va.x, va.y}; u2[1] = v2f{va.z, va.w};                  \
            u2[2] = v2f{vb.x, vb.y}; u2[3] = v2f{vb.z, vb.w};                  \
        }                                                                      \
        float dt0, dt1, dt2, dt3;                                              \
        {                                                                      \
            v2f d0 = pk_fma(q2[0][3], k2[3], pk_fma(q2[0][2], k2[2],           \
                     pk_fma(q2[0][1], k2[1], pk_mul(q2[0][0], k2[0]))));       \
            v2f d1 = pk_fma(q2[1][3], k2[3], pk_fma(q2[1][2], k2[2],           \
                     pk_fma(q2[1][1], k2[1], pk_mul(q2[1][0], k2[0]))));       \
            v2f d2 = pk_fma(q2[2][3], k2[3], pk_fma(q2[2][2], k2[2],           \
                     pk_fma(q2[2][1], k2[1], pk_mul(q2[2][0], k2[0]))));       \
            v2f d3 = pk_fma(q2[3][3], k2[3], pk_fma(q2[3][2], k2[2],           \
                     pk_fma(q2[3][1], k2[1], pk_mul(q2[3][0], k2[0]))));       \
            dt0 = d0.x + d0.y; dt1 = d1.x + d1.y;                              \
            dt2 = d2.x + d2.y; dt3 = d3.x + d3.y;                              \
        }                                                                      \
        ROR4(8, dt0, dt1, dt2, dt3);                                           \
        ROR4(4, dt0, dt1, dt2, dt3);                                           \
        ROR4(2, dt0, dt1, dt2, dt3);                                           \
        ROR4(1, dt0, dt1, dt2, dt3);                                           \
        if (act) {                                                             \
            float wg0 = __expf(dt0), wg1 = __expf(dt1);                        \
            float wg2 = __expf(dt2), wg3 = __expf(dt3);                        \
            l[0] += wg0; l[1] += wg1; l[2] += wg2; l[3] += wg3;                \
            v2f w0 = v2f{wg0, wg0}, w1 = v2f{wg1, wg1};                        \
            v2f w2 = v2f{wg2, wg2}, w3 = v2f{wg3, wg3};                        \
            _Pragma("unroll")                                                  \
            for (int j = 0; j < 4; j++) {                                      \
                acc2[0][j] = pk_fma(w0, u2[j], acc2[0][j]);                    \
                acc2[1][j] = pk_fma(w1, u2[j], acc2[1][j]);                    \
                acc2[2][j] = pk_fma(w2, u2[j], acc2[2][j]);                    \
                acc2[3][j] = pk_fma(w3, u2[j], acc2[3][j]);                    \
            }                                                                  \
        }                                                                      \
    }

    #pragma unroll 2
    for (int it = 0; it < nfull; it++) BODY(false)
    if (tail) { int it = nfull; BODY(true) }
#undef BODY

    // ---- reduce across the 4 groups ----
    #pragma unroll
    for (int h = 0; h < G; h++) {
        l[h] += __shfl_xor(l[h], 16, 64);
        l[h] += __shfl_xor(l[h], 32, 64);
        #pragma unroll
        for (int j = 0; j < 4; j++) {
            float ax = acc2[h][j].x, ay = acc2[h][j].y;
            ax += __shfl_xor(ax, 16, 64); ax += __shfl_xor(ax, 32, 64);
            ay += __shfl_xor(ay, 16, 64); ay += __shfl_xor(ay, 32, 64);
            acc2[h][j] = v2f{ax, ay};
        }
    }
    if (lane < 16) {
        #pragma unroll
        for (int h = 0; h < G; h++)
            #pragma unroll
            for (int j = 0; j < 4; j++) {
                s_wacc[w][h][sub * 8 + 2 * j]     = acc2[h][j].x;
                s_wacc[w][h][sub * 8 + 2 * j + 1] = acc2[h][j].y;
            }
    }
    if (lane == 0) {
        #pragma unroll
        for (int h = 0; h < G; h++) s_wl[w][h] = l[h];
    }
    __syncthreads();

    const size_t slot_base = (size_t)blockIdx.x * (G * DHEAD);
    for (int idx = tid; idx < G * DHEAD; idx += NT) {
        float s = s_wacc[0][idx >> 7][idx & 127] + s_wacc[1][idx >> 7][idx & 127]
                + s_wacc[2][idx >> 7][idx & 127] + s_wacc[3][idx >> 7][idx & 127];
        wsacc[slot_base + idx] = s;
    }
    if (tid < G) {
        wsl[(size_t)blockIdx.x * G + tid] =
            s_wl[0][tid] + s_wl[1][tid] + s_wl[2][tid] + s_wl[3][tid];
    }
}

__global__ __launch_bounds__(512) void paged_attn_combine(
    const int*   __restrict__ context_lens,
    const float* __restrict__ wsacc,
    const float* __restrict__ wsl,
    float*       __restrict__ out)
{
    const int bkv = blockIdx.x;
    const int kv  = bkv & 7;
    const int b   = bkv >> 3;
    const int t   = threadIdx.x;
    const int h   = t >> 7;
    const int d   = t & 127;

    const int len = context_lens[b] + 1;
    const int nch = (len + CHUNK - 1) >> 8;

    float asum = 0.f, lsum = 0.f;
    for (int cc = 0; cc < nch; cc++) {
        asum += wsacc[((size_t)bkv * MAXCH + cc) * (G * DHEAD) + t];
        lsum += wsl[((size_t)bkv * MAXCH + cc) * G + h];
    }
    out[((size_t)b * HQ + kv * G + h) * DHEAD + d] = asum / lsum;
}

extern "C" void kernel_launch(void* const* d_in, const int* in_sizes, int n_in,
                              void* d_out, int out_size, void* d_ws, size_t ws_size,
                              hipStream_t stream) {
    const float* query        = (const float*)d_in[0];
    const float* new_k        = (const float*)d_in[1];
    const float* new_v        = (const float*)d_in[2];
    const float* k_cache      = (const float*)d_in[3];
    const float* v_cache      = (const float*)d_in[4];
    const int*   block_table  = (const int*)d_in[5];
    const int*   context_lens = (const int*)d_in[6];
    float* out = (float*)d_out;

    float* wsacc = (float*)d_ws;
    float* wsl   = wsacc + (size_t)NSLOT * G * DHEAD;

    paged_attn_chunk<<<dim3(BATCH * HKV * MAXCH), dim3(NT), 0, stream>>>(
        query, new_k, new_v, k_cache, v_cache, block_table, context_lens,
        wsacc, wsl);
    paged_attn_combine<<<dim3(BATCH * HKV), dim3(512), 0, stream>>>(
        context_lens, wsacc, wsl, out);
}